// Round 1
// baseline (704.434 us; speedup 1.0000x reference)
//
#include <hip/hip_runtime.h>
#include <math.h>

// PersistenceLoss: BCE(y_true, y_pred) + 0.005 * topo
// topo: per 64x64 patch, sort values of both tensors, mean squared diff of
// aligned order statistics; mean over patches and batch.
// B=64, C=1, H=W=512, ts=64 -> 4096 patches total, 4096 elems each.

#define THREADS 256
#define PATCH_N 4096   // elements per patch
#define NBLOCKS 4096   // total patches (64 batch * 64 patches)

__global__ __launch_bounds__(THREADS) void patch_sort_kernel(
    const float* __restrict__ y_true,
    const float* __restrict__ y_pred,
    float2* __restrict__ partials)
{
    __shared__ float tp[PATCH_N];
    __shared__ float pp[PATCH_N];

    const int bp  = blockIdx.x;      // 0..4095
    const int b   = bp >> 6;         // batch index
    const int p   = bp & 63;         // patch index within image
    const int pr  = p >> 3;          // patch row (8 per side)
    const int pc  = p & 7;           // patch col
    const size_t base = (size_t)b * (512 * 512)
                      + (size_t)pr * (64 * 512)
                      + (size_t)pc * 64;

    const int tid = threadIdx.x;

    // ---- load patch into LDS + fused BCE partial ----
    float bce = 0.0f;
    #pragma unroll
    for (int s = 0; s < PATCH_N / THREADS; ++s) {
        int l = tid + s * THREADS;          // 0..4095 patch-linear
        int i = l >> 6;                     // row within patch
        int j = l & 63;                     // col within patch
        size_t g = base + (size_t)i * 512 + (size_t)j;
        float yt = y_true[g];
        float yp = y_pred[g];
        tp[l] = yt;
        pp[l] = yp;
        float pcl = fminf(fmaxf(yp, 1e-7f), 1.0f - 1e-7f);
        bce -= yt * logf(pcl) + (1.0f - yt) * log1pf(-pcl);
    }
    __syncthreads();

    // ---- bitonic sort both arrays (same network, shared barriers) ----
    for (int k = 2; k <= PATCH_N; k <<= 1) {
        for (int j = k >> 1; j > 0; j >>= 1) {
            const int jm1 = j - 1;
            #pragma unroll
            for (int s = 0; s < (PATCH_N / 2) / THREADS; ++s) {
                int t = tid + s * THREADS;                  // pair index 0..2047
                int i = ((t & ~jm1) << 1) | (t & jm1);      // insert 0 at bit log2(j)
                int ixj = i | j;
                bool up = ((i & k) == 0);

                float a0 = tp[i], a1 = tp[ixj];
                float lo = fminf(a0, a1), hi = fmaxf(a0, a1);
                tp[i]   = up ? lo : hi;
                tp[ixj] = up ? hi : lo;

                float b0 = pp[i], b1 = pp[ixj];
                float plo = fminf(b0, b1), phi = fmaxf(b0, b1);
                pp[i]   = up ? plo : phi;
                pp[ixj] = up ? phi : plo;
            }
            __syncthreads();
        }
    }

    // ---- squared diff of aligned order statistics ----
    float sq = 0.0f;
    #pragma unroll
    for (int s = 0; s < PATCH_N / THREADS; ++s) {
        int l = tid + s * THREADS;
        float d = pp[l] - tp[l];
        sq += d * d;
    }
    __syncthreads();

    // ---- block reduction (reuse LDS) ----
    tp[tid] = bce;
    pp[tid] = sq;
    __syncthreads();
    for (int off = THREADS / 2; off > 0; off >>= 1) {
        if (tid < off) {
            tp[tid] += tp[tid + off];
            pp[tid] += pp[tid + off];
        }
        __syncthreads();
    }
    if (tid == 0) {
        partials[bp] = make_float2(tp[0], pp[0]);
    }
}

__global__ __launch_bounds__(THREADS) void final_reduce_kernel(
    const float2* __restrict__ partials,
    float* __restrict__ out)
{
    __shared__ float rb[THREADS];
    __shared__ float rs[THREADS];
    const int tid = threadIdx.x;
    float b = 0.0f, s = 0.0f;
    for (int i = tid; i < NBLOCKS; i += THREADS) {
        float2 v = partials[i];
        b += v.x;
        s += v.y;
    }
    rb[tid] = b;
    rs[tid] = s;
    __syncthreads();
    for (int off = THREADS / 2; off > 0; off >>= 1) {
        if (tid < off) {
            rb[tid] += rb[tid + off];
            rs[tid] += rs[tid + off];
        }
        __syncthreads();
    }
    if (tid == 0) {
        // BCE mean and topo mean share the same denominator: 64*512*512
        out[0] = (rb[0] + 0.005f * rs[0]) * (1.0f / 16777216.0f);
    }
}

extern "C" void kernel_launch(void* const* d_in, const int* in_sizes, int n_in,
                              void* d_out, int out_size, void* d_ws, size_t ws_size,
                              hipStream_t stream) {
    const float* y_true = (const float*)d_in[0];
    const float* y_pred = (const float*)d_in[1];
    float* out = (float*)d_out;
    float2* partials = (float2*)d_ws;   // 4096 * 8 B = 32 KB

    hipLaunchKernelGGL(patch_sort_kernel, dim3(NBLOCKS), dim3(THREADS), 0, stream,
                       y_true, y_pred, partials);
    hipLaunchKernelGGL(final_reduce_kernel, dim3(1), dim3(THREADS), 0, stream,
                       partials, out);
}

// Round 2
// 245.669 us; speedup vs baseline: 2.8674x; 2.8674x over previous
//
#include <hip/hip_runtime.h>
#include <math.h>

// PersistenceLoss: BCE(y_true, y_pred) + 0.005 * topo
// topo: per 64x64 patch sort both tensors' values, mean squared diff of
// aligned order statistics. B=64, H=W=512 -> 4096 patches of 4096 elems.
//
// Register-blocked bitonic sort: 256 threads x 16 elems/thread.
//   j <= 8      : in-register compare-exchange (42 stages)
//   j = 16..512 : __shfl_xor within wave, mask = j/16 (33 stages)
//   j = 1024/2048: LDS, column-major buf[r*256+t] (stride-1, conflict-free)

#define THREADS 256
#define EPT 16
#define PATCH_N 4096
#define NBLOCKS 4096

__device__ __forceinline__ void ce(float& x, float& y, bool up) {
    float lo = fminf(x, y), hi = fmaxf(x, y);
    x = up ? lo : hi;
    y = up ? hi : lo;
}

// Full bitonic sort of 16 in-register elements.
// Phases k=2,4,8 have compile-time directions; k=16 phase direction = asc.
__device__ __forceinline__ void sort16(float v[EPT], bool asc) {
    #pragma unroll
    for (int k = 2; k <= 8; k <<= 1) {
        #pragma unroll
        for (int j = k >> 1; j >= 1; j >>= 1) {
            #pragma unroll
            for (int i = 0; i < EPT; ++i)
                if ((i & j) == 0)
                    ce(v[i], v[i | j], ((i & k) == 0));
        }
    }
    #pragma unroll
    for (int j = 8; j >= 1; j >>= 1) {
        #pragma unroll
        for (int i = 0; i < EPT; ++i)
            if ((i & j) == 0)
                ce(v[i], v[i | j], asc);
    }
}

// Bitonic merge of 16 in-register elements, uniform direction.
__device__ __forceinline__ void merge16(float v[EPT], bool up) {
    #pragma unroll
    for (int j = 8; j >= 1; j >>= 1) {
        #pragma unroll
        for (int i = 0; i < EPT; ++i)
            if ((i & j) == 0)
                ce(v[i], v[i | j], up);
    }
}

// Cross-lane stage: element stride j = MASK*16, partner lane = lane ^ MASK.
template<int MASK>
__device__ __forceinline__ void shfl_stage(float v[EPT], bool up, int t) {
    const bool keepmax = (up == ((t & MASK) != 0));
    #pragma unroll
    for (int i = 0; i < EPT; ++i) {
        float o = __shfl_xor(v[i], MASK, 64);
        float mn = fminf(v[i], o);
        float mx = fmaxf(v[i], o);
        v[i] = keepmax ? mx : mn;
    }
}

// Cross-wave stage via LDS: partner thread t^m (m = 64 or 128).
// Column-major layout buf[i*THREADS + t]: stride-1 across lanes on both
// write and read -> conflict-free.
__device__ __forceinline__ void lds_stage2(float a[EPT], float b[EPT],
                                           float* bufA, float* bufB,
                                           int t, int m, bool up) {
    #pragma unroll
    for (int i = 0; i < EPT; ++i) {
        bufA[i * THREADS + t] = a[i];
        bufB[i * THREADS + t] = b[i];
    }
    __syncthreads();
    const bool keepmax = (up == ((t & m) != 0));
    const int pt = t ^ m;
    #pragma unroll
    for (int i = 0; i < EPT; ++i) {
        float oa = bufA[i * THREADS + pt];
        float ob = bufB[i * THREADS + pt];
        a[i] = keepmax ? fmaxf(a[i], oa) : fminf(a[i], oa);
        b[i] = keepmax ? fmaxf(b[i], ob) : fminf(b[i], ob);
    }
    __syncthreads();
}

template<int K>
__device__ __forceinline__ void phase(float a[EPT], float b[EPT],
                                      float* bufA, float* bufB, int t) {
    const bool up = ((t & (K >> 4)) == 0);
    if constexpr (K >= 4096) lds_stage2(a, b, bufA, bufB, t, 128, up);
    if constexpr (K >= 2048) lds_stage2(a, b, bufA, bufB, t, 64, up);
    if constexpr (K >= 1024) { shfl_stage<32>(a, up, t); shfl_stage<32>(b, up, t); }
    if constexpr (K >= 512)  { shfl_stage<16>(a, up, t); shfl_stage<16>(b, up, t); }
    if constexpr (K >= 256)  { shfl_stage<8>(a, up, t);  shfl_stage<8>(b, up, t); }
    if constexpr (K >= 128)  { shfl_stage<4>(a, up, t);  shfl_stage<4>(b, up, t); }
    if constexpr (K >= 64)   { shfl_stage<2>(a, up, t);  shfl_stage<2>(b, up, t); }
    shfl_stage<1>(a, up, t);
    shfl_stage<1>(b, up, t);
    merge16(a, up);
    merge16(b, up);
}

__global__ __launch_bounds__(THREADS) void patch_sort_kernel(
    const float* __restrict__ y_true,
    const float* __restrict__ y_pred,
    float2* __restrict__ partials)
{
    __shared__ float bufA[PATCH_N];
    __shared__ float bufB[PATCH_N];

    const int bp = blockIdx.x;       // patch id 0..4095
    const int bb = bp >> 6;          // batch index
    const int p  = bp & 63;          // patch within image
    const int pr = p >> 3;
    const int pc = p & 7;
    const size_t base = (size_t)bb * (512 * 512)
                      + (size_t)pr * (64 * 512)
                      + (size_t)pc * 64;

    const int t = threadIdx.x;

    // Element e = t*16 + i: row = t>>2 (64 elems/row, 4 threads/row),
    // col = (t&3)*16 + i. 16B-aligned float4 loads.
    const size_t rowbase = base + (size_t)(t >> 2) * 512 + (size_t)(t & 3) * 16;

    float a[EPT], b[EPT];
    float bce = 0.0f;
    #pragma unroll
    for (int q = 0; q < 4; ++q) {
        float4 va = *reinterpret_cast<const float4*>(y_true + rowbase + q * 4);
        float4 vb = *reinterpret_cast<const float4*>(y_pred + rowbase + q * 4);
        a[q * 4 + 0] = va.x; a[q * 4 + 1] = va.y; a[q * 4 + 2] = va.z; a[q * 4 + 3] = va.w;
        b[q * 4 + 0] = vb.x; b[q * 4 + 1] = vb.y; b[q * 4 + 2] = vb.z; b[q * 4 + 3] = vb.w;
    }
    #pragma unroll
    for (int i = 0; i < EPT; ++i) {
        float yt = a[i];
        float pcl = fminf(fmaxf(b[i], 1e-7f), 1.0f - 1e-7f);
        bce -= yt * logf(pcl) + (1.0f - yt) * log1pf(-pcl);
    }

    // ---- sort both arrays ----
    const bool asc16 = ((t & 1) == 0);
    sort16(a, asc16);
    sort16(b, asc16);
    phase<32>(a, b, bufA, bufB, t);
    phase<64>(a, b, bufA, bufB, t);
    phase<128>(a, b, bufA, bufB, t);
    phase<256>(a, b, bufA, bufB, t);
    phase<512>(a, b, bufA, bufB, t);
    phase<1024>(a, b, bufA, bufB, t);
    phase<2048>(a, b, bufA, bufB, t);
    phase<4096>(a, b, bufA, bufB, t);

    // ---- squared diff of aligned order statistics ----
    float sq = 0.0f;
    #pragma unroll
    for (int i = 0; i < EPT; ++i) {
        float d = b[i] - a[i];
        sq += d * d;
    }

    // ---- block reduction: wave shuffle reduce, then 4 wave leaders ----
    #pragma unroll
    for (int off = 32; off >= 1; off >>= 1) {
        bce += __shfl_down(bce, off, 64);
        sq  += __shfl_down(sq, off, 64);
    }
    const int lane = t & 63;
    const int wid  = t >> 6;
    // last phase ended with register-only ops after its trailing barrier,
    // so bufA/bufB reuse here is safe after one more barrier
    __syncthreads();
    if (lane == 0) { bufA[wid] = bce; bufB[wid] = sq; }
    __syncthreads();
    if (t == 0) {
        partials[bp] = make_float2(bufA[0] + bufA[1] + bufA[2] + bufA[3],
                                   bufB[0] + bufB[1] + bufB[2] + bufB[3]);
    }
}

__global__ __launch_bounds__(THREADS) void final_reduce_kernel(
    const float2* __restrict__ partials,
    float* __restrict__ out)
{
    __shared__ float rb[THREADS];
    __shared__ float rs[THREADS];
    const int tid = threadIdx.x;
    float bsum = 0.0f, ssum = 0.0f;
    for (int i = tid; i < NBLOCKS; i += THREADS) {
        float2 v = partials[i];
        bsum += v.x;
        ssum += v.y;
    }
    rb[tid] = bsum;
    rs[tid] = ssum;
    __syncthreads();
    for (int off = THREADS / 2; off > 0; off >>= 1) {
        if (tid < off) {
            rb[tid] += rb[tid + off];
            rs[tid] += rs[tid + off];
        }
        __syncthreads();
    }
    if (tid == 0) {
        // BCE mean and topo mean share denominator 64*512*512 = 16777216
        out[0] = (rb[0] + 0.005f * rs[0]) * (1.0f / 16777216.0f);
    }
}

extern "C" void kernel_launch(void* const* d_in, const int* in_sizes, int n_in,
                              void* d_out, int out_size, void* d_ws, size_t ws_size,
                              hipStream_t stream) {
    const float* y_true = (const float*)d_in[0];
    const float* y_pred = (const float*)d_in[1];
    float* out = (float*)d_out;
    float2* partials = (float2*)d_ws;   // 4096 * 8 B = 32 KB

    hipLaunchKernelGGL(patch_sort_kernel, dim3(NBLOCKS), dim3(THREADS), 0, stream,
                       y_true, y_pred, partials);
    hipLaunchKernelGGL(final_reduce_kernel, dim3(1), dim3(THREADS), 0, stream,
                       partials, out);
}